// Round 1
// baseline (893.277 us; speedup 1.0000x reference)
//
#include <hip/hip_runtime.h>

#define NN 50000
#define EE 1600000
#define FD 128
#define GG 128
#define NC 10
#define NB_N 196   // ceil(50000/256)

// ---------------- CSR build ----------------
__global__ void k_zero_int(int* __restrict__ p, int n){
  int i = blockIdx.x * 256 + threadIdx.x;
  if (i < n) p[i] = 0;
}

__global__ void k_count(const int* __restrict__ dstI, int* __restrict__ deg){
  int e = blockIdx.x * 256 + threadIdx.x;   // grid exactly covers EE
  atomicAdd(&deg[dstI[e]], 1);
}

__global__ void k_scan1(const int* __restrict__ deg, int* __restrict__ excl, int* __restrict__ bsums){
  __shared__ int s[256];
  int t = threadIdx.x;
  int i = blockIdx.x * 256 + t;
  int v = (i < NN) ? deg[i] : 0;
  s[t] = v;
  __syncthreads();
  #pragma unroll
  for (int off = 1; off < 256; off <<= 1){
    int a = (t >= off) ? s[t - off] : 0;
    __syncthreads();
    s[t] += a;
    __syncthreads();
  }
  if (i < NN) excl[i] = s[t] - v;
  if (t == 255) bsums[blockIdx.x] = s[255];
}

__global__ void k_scan2(int* __restrict__ bsums, int nb){
  __shared__ int s[256];
  int t = threadIdx.x;
  int v = (t < nb) ? bsums[t] : 0;
  s[t] = v;
  __syncthreads();
  #pragma unroll
  for (int off = 1; off < 256; off <<= 1){
    int a = (t >= off) ? s[t - off] : 0;
    __syncthreads();
    s[t] += a;
    __syncthreads();
  }
  if (t < nb) bsums[t] = s[t] - v;   // exclusive block offsets
}

__global__ void k_scan3(int* __restrict__ rs, int* __restrict__ cur,
                        const int* __restrict__ excl, const int* __restrict__ bsums){
  int i = blockIdx.x * 256 + threadIdx.x;
  if (i < NN){
    int v = excl[i] + bsums[blockIdx.x];
    rs[i]  = v;
    cur[i] = v;
  }
}

__global__ void k_fill(const int* __restrict__ srcI, const int* __restrict__ dstI,
                       int* __restrict__ cur, int* __restrict__ adj){
  int e = blockIdx.x * 256 + threadIdx.x;
  int d = dstI[e];
  int slot = atomicAdd(&cur[d], 1);
  adj[slot] = srcI[e];
}

// ---------------- aggregation: h[i] = x[i] + sum_{j in adj(i)} x[j] ----------------
__global__ __launch_bounds__(256) void k_agg(const float* __restrict__ x, float* __restrict__ h,
                                             const int* __restrict__ adj,
                                             const int* __restrict__ rs,
                                             const int* __restrict__ deg){
  int t = threadIdx.x;
  int node = blockIdx.x * 8 + (t >> 5);   // grid exactly covers NN (6250*8)
  int lane = t & 31;
  const float4* xv = (const float4*)x;
  float4 acc = xv[(long)node * 32 + lane];
  int r0 = rs[node];
  int d  = deg[node];
  int j = 0;
  for (; j + 4 <= d; j += 4){
    int s0 = adj[r0 + j + 0];
    int s1 = adj[r0 + j + 1];
    int s2 = adj[r0 + j + 2];
    int s3 = adj[r0 + j + 3];
    float4 v0 = xv[(long)s0 * 32 + lane];
    float4 v1 = xv[(long)s1 * 32 + lane];
    float4 v2 = xv[(long)s2 * 32 + lane];
    float4 v3 = xv[(long)s3 * 32 + lane];
    acc.x += v0.x + v1.x + v2.x + v3.x;
    acc.y += v0.y + v1.y + v2.y + v3.y;
    acc.z += v0.z + v1.z + v2.z + v3.z;
    acc.w += v0.w + v1.w + v2.w + v3.w;
  }
  for (; j < d; ++j){
    int s0 = adj[r0 + j];
    float4 v0 = xv[(long)s0 * 32 + lane];
    acc.x += v0.x; acc.y += v0.y; acc.z += v0.z; acc.w += v0.w;
  }
  ((float4*)h)[(long)node * 32 + lane] = acc;
}

// ---------------- GEMM: out = epilogue(A @ W + b), A:[NN][128], W:[128][128] ----------------
// MODE 0: relu(A@W + b)
// MODE 1: relu(BN(A@W + b))  with eval-mode BN folded to scale/shift
template<int MODE>
__global__ __launch_bounds__(256, 2) void k_gemm(const float* __restrict__ A,
                                                 const float* __restrict__ W,
                                                 const float* __restrict__ bias,
                                                 const float* __restrict__ gma,
                                                 const float* __restrict__ bta,
                                                 const float* __restrict__ rmn,
                                                 const float* __restrict__ rvr,
                                                 float* __restrict__ out){
  __shared__ float Wl[128 * 128];   // 64 KB
  __shared__ float hs[32][128];     // 16 KB  -> 80 KB total, 2 blocks/CU
  int t = threadIdx.x;
  long row0 = (long)blockIdx.x * 32;

  // stage W (16384 floats = 4096 float4)
  {
    const float4* Wv = (const float4*)W;
    float4* Wlv = (float4*)Wl;
    #pragma unroll
    for (int i = 0; i < 16; ++i) Wlv[t + 256 * i] = Wv[t + 256 * i];
  }
  // stage 32 rows of A (4096 floats = 1024 float4)
  {
    const float4* Av = (const float4*)A;
    float4* hv = (float4*)hs;
    #pragma unroll
    for (int i = 0; i < 4; ++i){
      int idx = t + 256 * i;          // 0..1023 : row = idx>>5, colgrp = idx&31
      int r = idx >> 5;
      long grow = row0 + r;
      float4 v = make_float4(0.f, 0.f, 0.f, 0.f);
      if (grow < NN) v = Av[grow * 32 + (idx & 31)];
      hv[idx] = v;
    }
  }
  __syncthreads();

  int cg = t & 31;        // column group (4 cols)
  int rg = t >> 5;        // row sub-index 0..7
  int c0 = cg * 4;
  float acc[4][4] = {};

  for (int k0 = 0; k0 < 128; k0 += 4){
    float4 a0 = *(const float4*)&hs[rg +  0][k0];
    float4 a1 = *(const float4*)&hs[rg +  8][k0];
    float4 a2 = *(const float4*)&hs[rg + 16][k0];
    float4 a3 = *(const float4*)&hs[rg + 24][k0];
    const float* pa0 = (const float*)&a0;
    const float* pa1 = (const float*)&a1;
    const float* pa2 = (const float*)&a2;
    const float* pa3 = (const float*)&a3;
    #pragma unroll
    for (int kk = 0; kk < 4; ++kk){
      float4 w = *(const float4*)&Wl[(k0 + kk) * 128 + c0];
      acc[0][0] += pa0[kk] * w.x; acc[0][1] += pa0[kk] * w.y; acc[0][2] += pa0[kk] * w.z; acc[0][3] += pa0[kk] * w.w;
      acc[1][0] += pa1[kk] * w.x; acc[1][1] += pa1[kk] * w.y; acc[1][2] += pa1[kk] * w.z; acc[1][3] += pa1[kk] * w.w;
      acc[2][0] += pa2[kk] * w.x; acc[2][1] += pa2[kk] * w.y; acc[2][2] += pa2[kk] * w.z; acc[2][3] += pa2[kk] * w.w;
      acc[3][0] += pa3[kk] * w.x; acc[3][1] += pa3[kk] * w.y; acc[3][2] += pa3[kk] * w.z; acc[3][3] += pa3[kk] * w.w;
    }
  }

  // epilogue params for this thread's 4 columns
  float4 bb = *(const float4*)&bias[c0];
  float4 sc = make_float4(1.f, 1.f, 1.f, 1.f);
  float4 sh = make_float4(0.f, 0.f, 0.f, 0.f);
  if (MODE == 1){
    float4 g4 = *(const float4*)&gma[c0];
    float4 b4 = *(const float4*)&bta[c0];
    float4 m4 = *(const float4*)&rmn[c0];
    float4 v4 = *(const float4*)&rvr[c0];
    sc.x = g4.x * rsqrtf(v4.x + 1e-5f); sh.x = b4.x - m4.x * sc.x;
    sc.y = g4.y * rsqrtf(v4.y + 1e-5f); sh.y = b4.y - m4.y * sc.y;
    sc.z = g4.z * rsqrtf(v4.z + 1e-5f); sh.z = b4.z - m4.z * sc.z;
    sc.w = g4.w * rsqrtf(v4.w + 1e-5f); sh.w = b4.w - m4.w * sc.w;
  }

  float4* ov = (float4*)out;
  #pragma unroll
  for (int ri = 0; ri < 4; ++ri){
    long grow = row0 + rg + 8 * ri;
    if (grow >= NN) continue;
    float4 o;
    o.x = acc[ri][0] + bb.x;
    o.y = acc[ri][1] + bb.y;
    o.z = acc[ri][2] + bb.z;
    o.w = acc[ri][3] + bb.w;
    if (MODE == 1){
      o.x = o.x * sc.x + sh.x;
      o.y = o.y * sc.y + sh.y;
      o.z = o.z * sc.z + sh.z;
      o.w = o.w * sc.w + sh.w;
    }
    o.x = fmaxf(o.x, 0.f); o.y = fmaxf(o.y, 0.f); o.z = fmaxf(o.z, 0.f); o.w = fmaxf(o.w, 0.f);
    ov[grow * 32 + cg] = o;
  }
}

// ---------------- mean pool per graph (batch is sorted) ----------------
__global__ __launch_bounds__(256) void k_pool(const float* __restrict__ x,
                                              const int* __restrict__ batch,
                                              float* __restrict__ pooled){
  int g = blockIdx.x;
  // lower_bound(g), lower_bound(g+1)
  int lo, hi;
  { int a = 0, b = NN; while (a < b){ int m = (a + b) >> 1; if (batch[m] < g) a = m + 1; else b = m; } lo = a; }
  { int a = lo, b = NN; while (a < b){ int m = (a + b) >> 1; if (batch[m] < g + 1) a = m + 1; else b = m; } hi = a; }
  int t = threadIdx.x;
  int c = t & 127;
  int half = t >> 7;
  float acc = 0.f;
  for (int i = lo + half; i < hi; i += 2) acc += x[(long)i * 128 + c];
  __shared__ float s[256];
  s[t] = acc;
  __syncthreads();
  if (t < 128){
    float v = s[t] + s[t + 128];
    int cnt = hi - lo;
    float denom = (cnt > 0) ? (float)cnt : 1.0f;
    pooled[g * 128 + t] = v / denom;
  }
}

// ---------------- head: logits + log_softmax ----------------
__global__ void k_head(const float* __restrict__ pooled, const float* __restrict__ fcw,
                       const float* __restrict__ fcb, float* __restrict__ out){
  int g = threadIdx.x;   // 128 threads, 1 block
  float logit[NC];
  #pragma unroll
  for (int c = 0; c < NC; ++c) logit[c] = fcb[c];
  for (int k = 0; k < 128; ++k){
    float pv = pooled[g * 128 + k];
    #pragma unroll
    for (int c = 0; c < NC; ++c) logit[c] += pv * fcw[k * NC + c];
  }
  float m = logit[0];
  #pragma unroll
  for (int c = 1; c < NC; ++c) m = fmaxf(m, logit[c]);
  float sum = 0.f;
  #pragma unroll
  for (int c = 0; c < NC; ++c) sum += expf(logit[c] - m);
  float ls = logf(sum);
  #pragma unroll
  for (int c = 0; c < NC; ++c) out[g * NC + c] = logit[c] - m - ls;
}

extern "C" void kernel_launch(void* const* d_in, const int* in_sizes, int n_in,
                              void* d_out, int out_size, void* d_ws, size_t ws_size,
                              hipStream_t stream) {
  const float* x     = (const float*)d_in[0];
  const int*   eidx  = (const int*)  d_in[1];
  const int*   batch = (const int*)  d_in[2];
  const float* W1    = (const float*)d_in[3];
  const float* b1    = (const float*)d_in[4];
  const float* W2    = (const float*)d_in[5];
  const float* b2    = (const float*)d_in[6];
  const float* gma   = (const float*)d_in[7];
  const float* bta   = (const float*)d_in[8];
  const float* rmn   = (const float*)d_in[9];
  const float* rvr   = (const float*)d_in[10];
  const float* fcw   = (const float*)d_in[11];
  const float* fcb   = (const float*)d_in[12];
  float* out = (float*)d_out;

  const int* srcI = eidx;          // edge_index[0]
  const int* dstI = eidx + EE;     // edge_index[1]

  // workspace carve
  float* hA   = (float*)d_ws;
  float* hB   = hA + 6400000;            // 25.6 MB each
  int*   adj  = (int*)(hB + 6400000);    // 6.4 MB
  int*   deg  = adj + EE;
  int*   excl = deg + 50048;
  int*   rs   = excl + 50048;
  int*   cur  = rs + 50048;
  int*   bs   = cur + 50048;             // 256 ints
  float* pooled = (float*)(bs + 256);    // 64 KB

  // build CSR
  k_zero_int<<<NB_N, 256, 0, stream>>>(deg, NN);
  k_count   <<<EE / 256, 256, 0, stream>>>(dstI, deg);
  k_scan1   <<<NB_N, 256, 0, stream>>>(deg, excl, bs);
  k_scan2   <<<1, 256, 0, stream>>>(bs, NB_N);
  k_scan3   <<<NB_N, 256, 0, stream>>>(rs, cur, excl, bs);
  k_fill    <<<EE / 256, 256, 0, stream>>>(srcI, dstI, cur, adj);

  const float* cx = x;
  float* bufs[2] = { hA, hB };
  int cb = 0;
  for (int l = 0; l < 3; ++l){
    float* hagg = bufs[cb];
    float* ht   = bufs[cb ^ 1];
    k_agg<<<NN / 8, 256, 0, stream>>>(cx, hagg, adj, rs, deg);
    k_gemm<0><<<(NN + 31) / 32, 256, 0, stream>>>(hagg, W1 + l * 16384, b1 + l * 128,
                                                  nullptr, nullptr, nullptr, nullptr, ht);
    k_gemm<1><<<(NN + 31) / 32, 256, 0, stream>>>(ht, W2 + l * 16384, b2 + l * 128,
                                                  gma + l * 128, bta + l * 128,
                                                  rmn + l * 128, rvr + l * 128, hagg);
    cx = hagg;
    cb ^= 1;
  }

  k_pool<<<GG, 256, 0, stream>>>(cx, batch, pooled);
  k_head<<<1, 128, 0, stream>>>(pooled, fcw, fcb, out);
}

// Round 2
// 598.683 us; speedup vs baseline: 1.4921x; 1.4921x over previous
//
#include <hip/hip_runtime.h>

#define NN 50000
#define EE 1600000
#define GG 128
#define NC 10
#define NB_N 196   // ceil(50000/256)

typedef __attribute__((ext_vector_type(8))) short bf16x8;
typedef __attribute__((ext_vector_type(4))) float f32x4;
typedef unsigned short u16;

__device__ inline u16 f2bf(float x){
  unsigned u = __builtin_bit_cast(unsigned, x);
  u += 0x7fffu + ((u >> 16) & 1u);          // RNE
  return (u16)(u >> 16);
}
__device__ inline float bf2f(u16 u){
  return __builtin_bit_cast(float, ((unsigned)u) << 16);
}

// ---------------- CSR build ----------------
__global__ void k_zero_int(int* __restrict__ p, int n){
  int i = blockIdx.x * 256 + threadIdx.x;
  if (i < n) p[i] = 0;
}

__global__ void k_count(const int* __restrict__ dstI, int* __restrict__ deg){
  long base = (long)blockIdx.x * 2048 + threadIdx.x;
  if (blockIdx.x < 781){
    int d[8];
    #pragma unroll
    for (int j = 0; j < 8; ++j) d[j] = dstI[base + j * 256];
    #pragma unroll
    for (int j = 0; j < 8; ++j) atomicAdd(&deg[d[j]], 1);
  } else {
    #pragma unroll
    for (int j = 0; j < 8; ++j){
      long e = base + j * 256;
      if (e < EE) atomicAdd(&deg[dstI[e]], 1);
    }
  }
}

__global__ void k_scan1(const int* __restrict__ deg, int* __restrict__ excl, int* __restrict__ bsums){
  __shared__ int s[256];
  int t = threadIdx.x;
  int i = blockIdx.x * 256 + t;
  int v = (i < NN) ? deg[i] : 0;
  s[t] = v;
  __syncthreads();
  #pragma unroll
  for (int off = 1; off < 256; off <<= 1){
    int a = (t >= off) ? s[t - off] : 0;
    __syncthreads();
    s[t] += a;
    __syncthreads();
  }
  if (i < NN) excl[i] = s[t] - v;
  if (t == 255) bsums[blockIdx.x] = s[255];
}

__global__ void k_scan2(int* __restrict__ bsums, int nb){
  __shared__ int s[256];
  int t = threadIdx.x;
  int v = (t < nb) ? bsums[t] : 0;
  s[t] = v;
  __syncthreads();
  #pragma unroll
  for (int off = 1; off < 256; off <<= 1){
    int a = (t >= off) ? s[t - off] : 0;
    __syncthreads();
    s[t] += a;
    __syncthreads();
  }
  if (t < nb) bsums[t] = s[t] - v;
}

__global__ void k_scan3(int* __restrict__ rs, int* __restrict__ cur,
                        const int* __restrict__ excl, const int* __restrict__ bsums){
  int i = blockIdx.x * 256 + threadIdx.x;
  if (i < NN){
    int v = excl[i] + bsums[blockIdx.x];
    rs[i]  = v;
    cur[i] = v;
  }
}

__global__ void k_fill(const int* __restrict__ srcI, const int* __restrict__ dstI,
                       int* __restrict__ cur, int* __restrict__ adj){
  long base = (long)blockIdx.x * 2048 + threadIdx.x;
  if (blockIdx.x < 781){
    int d[8], s[8], slot[8];
    #pragma unroll
    for (int j = 0; j < 8; ++j) d[j] = dstI[base + j * 256];
    #pragma unroll
    for (int j = 0; j < 8; ++j) s[j] = srcI[base + j * 256];
    #pragma unroll
    for (int j = 0; j < 8; ++j) slot[j] = atomicAdd(&cur[d[j]], 1);
    #pragma unroll
    for (int j = 0; j < 8; ++j) adj[slot[j]] = s[j];
  } else {
    #pragma unroll
    for (int j = 0; j < 8; ++j){
      long e = base + j * 256;
      if (e < EE){
        int slot = atomicAdd(&cur[dstI[e]], 1);
        adj[slot] = srcI[e];
      }
    }
  }
}

// ---------------- prep: x->bf16, W->bf16 transposed, BN fold ----------------
__global__ void k_cvt_x(const float* __restrict__ x, u16* __restrict__ xb){
  int i = blockIdx.x * 256 + threadIdx.x;       // grid covers N*128/4 exactly
  float4 v = ((const float4*)x)[i];
  ushort4 o;
  o.x = f2bf(v.x); o.y = f2bf(v.y); o.z = f2bf(v.z); o.w = f2bf(v.w);
  ((ushort4*)xb)[i] = o;
}

__global__ void k_prep_w(const float* __restrict__ W1, const float* __restrict__ W2,
                         u16* __restrict__ Wt){
  int i = blockIdx.x * 256 + threadIdx.x;       // 0..98303
  int a = i >> 14; int r = i & 16383; int n = r >> 7; int k = r & 127;
  const float* Wsrc = (a < 3) ? (W1 + a * 16384) : (W2 + (a - 3) * 16384);
  Wt[a * 16384 + n * 128 + k] = f2bf(Wsrc[k * 128 + n]);
}

__global__ void k_prep_scsh(const float* __restrict__ b1, const float* __restrict__ b2,
                            const float* __restrict__ gma, const float* __restrict__ bta,
                            const float* __restrict__ rmn, const float* __restrict__ rvr,
                            float* __restrict__ SC, float* __restrict__ SH){
  int i = blockIdx.x * 256 + threadIdx.x;
  if (i < 768){
    int l = i >> 8; int r = i & 255; int mode = r >> 7; int c = r & 127;
    if (mode == 0){
      SC[(l * 2) * 128 + c] = 1.0f;
      SH[(l * 2) * 128 + c] = b1[l * 128 + c];
    } else {
      float S = gma[l * 128 + c] * rsqrtf(rvr[l * 128 + c] + 1e-5f);
      SC[(l * 2 + 1) * 128 + c] = S;
      SH[(l * 2 + 1) * 128 + c] = (b2[l * 128 + c] - rmn[l * 128 + c]) * S + bta[l * 128 + c];
    }
  }
}

// ---------------- aggregation (bf16 rows, fp32 accumulate) ----------------
__global__ __launch_bounds__(256) void k_agg(const u16* __restrict__ xb, u16* __restrict__ hb,
                                             const int* __restrict__ adj,
                                             const int* __restrict__ rs,
                                             const int* __restrict__ deg){
  int t = threadIdx.x;
  int node = blockIdx.x * 8 + (t >> 5);   // grid = 6250 covers NN exactly
  int lane = t & 31;
  const ushort4* xv = (const ushort4*)xb; // 32 ushort4 per 128-wide row
  ushort4 sv = xv[(long)node * 32 + lane];
  float a0 = bf2f(sv.x), a1 = bf2f(sv.y), a2 = bf2f(sv.z), a3 = bf2f(sv.w);
  int r0 = rs[node];
  int d  = deg[node];
  int j = 0;
  for (; j + 4 <= d; j += 4){
    int s0 = adj[r0 + j + 0];
    int s1 = adj[r0 + j + 1];
    int s2 = adj[r0 + j + 2];
    int s3 = adj[r0 + j + 3];
    ushort4 v0 = xv[(long)s0 * 32 + lane];
    ushort4 v1 = xv[(long)s1 * 32 + lane];
    ushort4 v2 = xv[(long)s2 * 32 + lane];
    ushort4 v3 = xv[(long)s3 * 32 + lane];
    a0 += bf2f(v0.x) + bf2f(v1.x) + bf2f(v2.x) + bf2f(v3.x);
    a1 += bf2f(v0.y) + bf2f(v1.y) + bf2f(v2.y) + bf2f(v3.y);
    a2 += bf2f(v0.z) + bf2f(v1.z) + bf2f(v2.z) + bf2f(v3.z);
    a3 += bf2f(v0.w) + bf2f(v1.w) + bf2f(v2.w) + bf2f(v3.w);
  }
  for (; j < d; ++j){
    int s0 = adj[r0 + j];
    ushort4 v0 = xv[(long)s0 * 32 + lane];
    a0 += bf2f(v0.x); a1 += bf2f(v0.y); a2 += bf2f(v0.z); a3 += bf2f(v0.w);
  }
  ushort4 o;
  o.x = f2bf(a0); o.y = f2bf(a1); o.z = f2bf(a2); o.w = f2bf(a3);
  ((ushort4*)hb)[(long)node * 32 + lane] = o;
}

// ---------------- MFMA GEMM: Out = relu(A@W * SC + SH), all [*][128] ----------------
// Operand-swapped: D = mfma(Wfrag, Hfrag) -> lane holds 4 contiguous output cols.
__global__ __launch_bounds__(256, 2) void k_gemm(const u16* __restrict__ Ain,
                                                 const u16* __restrict__ Wt,
                                                 const float* __restrict__ SC,
                                                 const float* __restrict__ SH,
                                                 u16* __restrict__ Out){
  int gw = (blockIdx.x * 256 + threadIdx.x) >> 6;
  int l  = threadIdx.x & 63;
  int m  = l & 15;          // A-operand: output-col sub-index / B-operand: output-row sub-index
  int kb = l >> 4;          // k-block (8 bf16 each)
  const int NW = (gridDim.x * 256) >> 6;

  bf16x8 w[8][4];
  #pragma unroll
  for (int mt = 0; mt < 8; ++mt)
    #pragma unroll
    for (int ks = 0; ks < 4; ++ks)
      w[mt][ks] = *(const bf16x8*)(Wt + (mt * 16 + m) * 128 + ks * 32 + kb * 8);

  for (int tile = gw; tile < 3125; tile += NW){
    long row0 = (long)tile * 16;
    f32x4 acc[8] = {};
    #pragma unroll
    for (int ks = 0; ks < 4; ++ks){
      bf16x8 h = *(const bf16x8*)(Ain + (row0 + m) * 128 + ks * 32 + kb * 8);
      #pragma unroll
      for (int mt = 0; mt < 8; ++mt)
        acc[mt] = __builtin_amdgcn_mfma_f32_16x16x32_bf16(w[mt][ks], h, acc[mt], 0, 0, 0);
    }
    // lane output: row = row0 + m, cols = mt*16 + kb*4 + (0..3)
    #pragma unroll
    for (int mt = 0; mt < 8; ++mt){
      int c0 = mt * 16 + kb * 4;
      float4 sc = *(const float4*)(SC + c0);
      float4 sh = *(const float4*)(SH + c0);
      float v0 = fmaxf(acc[mt][0] * sc.x + sh.x, 0.f);
      float v1 = fmaxf(acc[mt][1] * sc.y + sh.y, 0.f);
      float v2 = fmaxf(acc[mt][2] * sc.z + sh.z, 0.f);
      float v3 = fmaxf(acc[mt][3] * sc.w + sh.w, 0.f);
      ushort4 o;
      o.x = f2bf(v0); o.y = f2bf(v1); o.z = f2bf(v2); o.w = f2bf(v3);
      *(ushort4*)(Out + (row0 + m) * 128 + c0) = o;
    }
  }
}

// ---------------- mean pool per graph (batch sorted) ----------------
__global__ __launch_bounds__(256) void k_pool(const u16* __restrict__ xb,
                                              const int* __restrict__ batch,
                                              float* __restrict__ pooled){
  int g = blockIdx.x;
  int lo, hi;
  { int a = 0, b = NN; while (a < b){ int mm = (a + b) >> 1; if (batch[mm] < g) a = mm + 1; else b = mm; } lo = a; }
  { int a = lo, b = NN; while (a < b){ int mm = (a + b) >> 1; if (batch[mm] < g + 1) a = mm + 1; else b = mm; } hi = a; }
  int t = threadIdx.x;
  int c = t & 127;
  int half = t >> 7;
  float acc = 0.f;
  for (int i = lo + half; i < hi; i += 2) acc += bf2f(xb[(long)i * 128 + c]);
  __shared__ float s[256];
  s[t] = acc;
  __syncthreads();
  if (t < 128){
    float v = s[t] + s[t + 128];
    int cnt = hi - lo;
    float denom = (cnt > 0) ? (float)cnt : 1.0f;
    pooled[g * 128 + t] = v / denom;
  }
}

// ---------------- head ----------------
__global__ void k_head(const float* __restrict__ pooled, const float* __restrict__ fcw,
                       const float* __restrict__ fcb, float* __restrict__ out){
  int g = threadIdx.x;   // 128 threads, 1 block
  float logit[NC];
  #pragma unroll
  for (int c = 0; c < NC; ++c) logit[c] = fcb[c];
  for (int k = 0; k < 128; ++k){
    float pv = pooled[g * 128 + k];
    #pragma unroll
    for (int c = 0; c < NC; ++c) logit[c] += pv * fcw[k * NC + c];
  }
  float m = logit[0];
  #pragma unroll
  for (int c = 1; c < NC; ++c) m = fmaxf(m, logit[c]);
  float sum = 0.f;
  #pragma unroll
  for (int c = 0; c < NC; ++c) sum += expf(logit[c] - m);
  float ls = logf(sum);
  #pragma unroll
  for (int c = 0; c < NC; ++c) out[g * NC + c] = logit[c] - m - ls;
}

extern "C" void kernel_launch(void* const* d_in, const int* in_sizes, int n_in,
                              void* d_out, int out_size, void* d_ws, size_t ws_size,
                              hipStream_t stream) {
  const float* x     = (const float*)d_in[0];
  const int*   eidx  = (const int*)  d_in[1];
  const int*   batch = (const int*)  d_in[2];
  const float* W1    = (const float*)d_in[3];
  const float* b1    = (const float*)d_in[4];
  const float* W2    = (const float*)d_in[5];
  const float* b2    = (const float*)d_in[6];
  const float* gma   = (const float*)d_in[7];
  const float* bta   = (const float*)d_in[8];
  const float* rmn   = (const float*)d_in[9];
  const float* rvr   = (const float*)d_in[10];
  const float* fcw   = (const float*)d_in[11];
  const float* fcb   = (const float*)d_in[12];
  float* out = (float*)d_out;

  const int* srcI = eidx;          // edge_index[0]
  const int* dstI = eidx + EE;     // edge_index[1]

  // workspace carve (ushort granularity for activations)
  u16* bufX = (u16*)d_ws;                 // 6.4M elems (12.8 MB)
  u16* bufA = bufX + 6400000;
  u16* bufB = bufA + 6400000;
  u16* Wt   = bufB + 6400000;             // 6*16384
  float* SC = (float*)(Wt + 98304);       // 768
  float* SH = SC + 768;                   // 768
  float* pooled = SH + 768;               // 16384
  int* adj  = (int*)(pooled + 16384);     // 1.6M
  int* deg  = adj + EE;
  int* excl = deg + 50048;
  int* rs   = excl + 50048;
  int* cur  = rs + 50048;
  int* bs   = cur + 50048;                // 256

  // CSR build
  k_zero_int<<<NB_N, 256, 0, stream>>>(deg, NN);
  k_count   <<<782, 256, 0, stream>>>(dstI, deg);
  k_scan1   <<<NB_N, 256, 0, stream>>>(deg, excl, bs);
  k_scan2   <<<1, 256, 0, stream>>>(bs, NB_N);
  k_scan3   <<<NB_N, 256, 0, stream>>>(rs, cur, excl, bs);
  k_fill    <<<782, 256, 0, stream>>>(srcI, dstI, cur, adj);

  // prep
  k_cvt_x    <<<6250, 256, 0, stream>>>(x, bufX);
  k_prep_w   <<<384, 256, 0, stream>>>(W1, W2, Wt);
  k_prep_scsh<<<3, 256, 0, stream>>>(b1, b2, gma, bta, rmn, rvr, SC, SH);

  // layer schedule (no aliasing hazards):
  // L1: agg X->A ; g0 A->B ; g1 B->A
  // L2: agg A->B ; g0 B->X ; g1 X->B
  // L3: agg B->A ; g0 A->X ; g1 X->A
  u16* aggin [3] = { bufX, bufA, bufB };
  u16* aggout[3] = { bufA, bufB, bufA };
  u16* g0out [3] = { bufB, bufX, bufX };
  u16* g1out [3] = { bufA, bufB, bufA };

  for (int l = 0; l < 3; ++l){
    k_agg <<<6250, 256, 0, stream>>>(aggin[l], aggout[l], adj, rs, deg);
    k_gemm<<<256, 256, 0, stream>>>(aggout[l], Wt + l * 16384,
                                    SC + (l * 2) * 128, SH + (l * 2) * 128, g0out[l]);
    k_gemm<<<256, 256, 0, stream>>>(g0out[l], Wt + (3 + l) * 16384,
                                    SC + (l * 2 + 1) * 128, SH + (l * 2 + 1) * 128, g1out[l]);
  }

  k_pool<<<GG, 256, 0, stream>>>(g1out[2], batch, pooled);
  k_head<<<1, 128, 0, stream>>>(pooled, fcw, fcb, out);
}

// Round 3
// 587.236 us; speedup vs baseline: 1.5212x; 1.0195x over previous
//
#include <hip/hip_runtime.h>

#define NN 50000
#define EE 1600000
#define GG 128
#define NC 10
#define NB_N 196   // ceil(50000/256)

typedef __attribute__((ext_vector_type(8))) short bf16x8;
typedef __attribute__((ext_vector_type(4))) float f32x4;
typedef unsigned short u16;

__device__ inline u16 f2bf(float x){
  unsigned u = __builtin_bit_cast(unsigned, x);
  u += 0x7fffu + ((u >> 16) & 1u);          // RNE
  return (u16)(u >> 16);
}
__device__ inline float bf2f(u16 u){
  return __builtin_bit_cast(float, ((unsigned)u) << 16);
}

// ---------------- CSR build ----------------
__global__ void k_zero_int(int* __restrict__ p, int n){
  int i = blockIdx.x * 256 + threadIdx.x;
  if (i < n) p[i] = 0;
}

__global__ void k_count(const int* __restrict__ dstI, int* __restrict__ deg){
  long base = (long)blockIdx.x * 2048 + threadIdx.x;
  if (blockIdx.x < 781){
    int d[8];
    #pragma unroll
    for (int j = 0; j < 8; ++j) d[j] = dstI[base + j * 256];
    #pragma unroll
    for (int j = 0; j < 8; ++j) atomicAdd(&deg[d[j]], 1);
  } else {
    #pragma unroll
    for (int j = 0; j < 8; ++j){
      long e = base + j * 256;
      if (e < EE) atomicAdd(&deg[dstI[e]], 1);
    }
  }
}

__global__ void k_scan1(const int* __restrict__ deg, int* __restrict__ excl, int* __restrict__ bsums){
  __shared__ int s[256];
  int t = threadIdx.x;
  int i = blockIdx.x * 256 + t;
  int v = (i < NN) ? deg[i] : 0;
  s[t] = v;
  __syncthreads();
  #pragma unroll
  for (int off = 1; off < 256; off <<= 1){
    int a = (t >= off) ? s[t - off] : 0;
    __syncthreads();
    s[t] += a;
    __syncthreads();
  }
  if (i < NN) excl[i] = s[t] - v;
  if (t == 255) bsums[blockIdx.x] = s[255];
}

__global__ void k_scan2(int* __restrict__ bsums, int nb){
  __shared__ int s[256];
  int t = threadIdx.x;
  int v = (t < nb) ? bsums[t] : 0;
  s[t] = v;
  __syncthreads();
  #pragma unroll
  for (int off = 1; off < 256; off <<= 1){
    int a = (t >= off) ? s[t - off] : 0;
    __syncthreads();
    s[t] += a;
    __syncthreads();
  }
  if (t < nb) bsums[t] = s[t] - v;
}

// rs + bucket cursors (bucket b = nodes [b*64, b*64+64), cursor padded to 64B lines)
__global__ void k_scan3(int* __restrict__ rs, int* __restrict__ bcur,
                        const int* __restrict__ excl, const int* __restrict__ bsums){
  int i = blockIdx.x * 256 + threadIdx.x;
  if (i < NN){
    int v = excl[i] + bsums[blockIdx.x];
    rs[i] = v;
    if ((i & 63) == 0) bcur[(i >> 6) * 16] = v;
    if (i == 0) rs[NN] = EE;
  }
}

// bin edges into 782 dst-range buckets; stage packed (localdst<<16 | src)
__global__ void k_bin(const int* __restrict__ srcI, const int* __restrict__ dstI,
                      int* __restrict__ bcur, int* __restrict__ stg){
  long base = (long)blockIdx.x * 2048 + threadIdx.x;
  if (blockIdx.x < 781){
    int d[8], s[8], pos[8];
    #pragma unroll
    for (int j = 0; j < 8; ++j) d[j] = dstI[base + j * 256];
    #pragma unroll
    for (int j = 0; j < 8; ++j) s[j] = srcI[base + j * 256];
    #pragma unroll
    for (int j = 0; j < 8; ++j) pos[j] = atomicAdd(&bcur[(d[j] >> 6) * 16], 1);
    #pragma unroll
    for (int j = 0; j < 8; ++j) stg[pos[j]] = s[j] | ((d[j] & 63) << 16);
  } else {
    #pragma unroll
    for (int j = 0; j < 8; ++j){
      long e = base + j * 256;
      if (e < EE){
        int d = dstI[e];
        int pos = atomicAdd(&bcur[(d >> 6) * 16], 1);
        stg[pos] = srcI[e] | ((d & 63) << 16);
      }
    }
  }
}

// per-bucket node-granular fill: single-writer 8KB region -> no cross-XCD line sharing
__global__ __launch_bounds__(256) void k_fill2(const int* __restrict__ stg,
                                               const int* __restrict__ rs,
                                               int* __restrict__ adj){
  __shared__ int lcur[64];
  int b = blockIdx.x;
  int n0 = b << 6;
  int t = threadIdx.x;
  int nn = NN - n0; if (nn > 64) nn = 64;
  int base = rs[n0];
  int end  = rs[n0 + nn];
  if (t < 64) lcur[t] = (t < nn) ? (rs[n0 + t] - base) : 0;
  __syncthreads();
  for (int i = base + t; i < end; i += 256){
    int e = stg[i];
    int slot = atomicAdd(&lcur[e >> 16], 1);
    adj[base + slot] = e & 0xffff;
  }
}

// ---------------- prep: x->bf16, W->bf16 transposed, BN fold ----------------
__global__ void k_cvt_x(const float* __restrict__ x, u16* __restrict__ xb){
  int i = blockIdx.x * 256 + threadIdx.x;       // grid covers N*128/4 exactly
  float4 v = ((const float4*)x)[i];
  ushort4 o;
  o.x = f2bf(v.x); o.y = f2bf(v.y); o.z = f2bf(v.z); o.w = f2bf(v.w);
  ((ushort4*)xb)[i] = o;
}

__global__ void k_prep_w(const float* __restrict__ W1, const float* __restrict__ W2,
                         u16* __restrict__ Wt){
  int i = blockIdx.x * 256 + threadIdx.x;       // 0..98303
  int a = i >> 14; int r = i & 16383; int n = r >> 7; int k = r & 127;
  const float* Wsrc = (a < 3) ? (W1 + a * 16384) : (W2 + (a - 3) * 16384);
  Wt[a * 16384 + n * 128 + k] = f2bf(Wsrc[k * 128 + n]);
}

__global__ void k_prep_scsh(const float* __restrict__ b1, const float* __restrict__ b2,
                            const float* __restrict__ gma, const float* __restrict__ bta,
                            const float* __restrict__ rmn, const float* __restrict__ rvr,
                            float* __restrict__ SC, float* __restrict__ SH){
  int i = blockIdx.x * 256 + threadIdx.x;
  if (i < 768){
    int l = i >> 8; int r = i & 255; int mode = r >> 7; int c = r & 127;
    if (mode == 0){
      SC[(l * 2) * 128 + c] = 1.0f;
      SH[(l * 2) * 128 + c] = b1[l * 128 + c];
    } else {
      float S = gma[l * 128 + c] * rsqrtf(rvr[l * 128 + c] + 1e-5f);
      SC[(l * 2 + 1) * 128 + c] = S;
      SH[(l * 2 + 1) * 128 + c] = (b2[l * 128 + c] - rmn[l * 128 + c]) * S + bta[l * 128 + c];
    }
  }
}

// ---------------- aggregation (bf16 rows, fp32 accumulate) ----------------
__global__ __launch_bounds__(256) void k_agg(const u16* __restrict__ xb, u16* __restrict__ hb,
                                             const int* __restrict__ adj,
                                             const int* __restrict__ rs,
                                             const int* __restrict__ deg){
  int t = threadIdx.x;
  int node = blockIdx.x * 8 + (t >> 5);   // grid = 6250 covers NN exactly
  int lane = t & 31;
  const ushort4* xv = (const ushort4*)xb; // 32 ushort4 per 128-wide row
  ushort4 sv = xv[(long)node * 32 + lane];
  float a0 = bf2f(sv.x), a1 = bf2f(sv.y), a2 = bf2f(sv.z), a3 = bf2f(sv.w);
  int r0 = rs[node];
  int d  = deg[node];
  int j = 0;
  for (; j + 4 <= d; j += 4){
    int s0 = adj[r0 + j + 0];
    int s1 = adj[r0 + j + 1];
    int s2 = adj[r0 + j + 2];
    int s3 = adj[r0 + j + 3];
    ushort4 v0 = xv[(long)s0 * 32 + lane];
    ushort4 v1 = xv[(long)s1 * 32 + lane];
    ushort4 v2 = xv[(long)s2 * 32 + lane];
    ushort4 v3 = xv[(long)s3 * 32 + lane];
    a0 += bf2f(v0.x) + bf2f(v1.x) + bf2f(v2.x) + bf2f(v3.x);
    a1 += bf2f(v0.y) + bf2f(v1.y) + bf2f(v2.y) + bf2f(v3.y);
    a2 += bf2f(v0.z) + bf2f(v1.z) + bf2f(v2.z) + bf2f(v3.z);
    a3 += bf2f(v0.w) + bf2f(v1.w) + bf2f(v2.w) + bf2f(v3.w);
  }
  for (; j < d; ++j){
    int s0 = adj[r0 + j];
    ushort4 v0 = xv[(long)s0 * 32 + lane];
    a0 += bf2f(v0.x); a1 += bf2f(v0.y); a2 += bf2f(v0.z); a3 += bf2f(v0.w);
  }
  ushort4 o;
  o.x = f2bf(a0); o.y = f2bf(a1); o.z = f2bf(a2); o.w = f2bf(a3);
  ((ushort4*)hb)[(long)node * 32 + lane] = o;
}

// ---------------- MFMA GEMM: Out = relu(A@W * SC + SH), all [*][128] ----------------
__global__ __launch_bounds__(256, 2) void k_gemm(const u16* __restrict__ Ain,
                                                 const u16* __restrict__ Wt,
                                                 const float* __restrict__ SC,
                                                 const float* __restrict__ SH,
                                                 u16* __restrict__ Out){
  int gw = (blockIdx.x * 256 + threadIdx.x) >> 6;
  int l  = threadIdx.x & 63;
  int m  = l & 15;
  int kb = l >> 4;
  const int NW = (gridDim.x * 256) >> 6;

  bf16x8 w[8][4];
  #pragma unroll
  for (int mt = 0; mt < 8; ++mt)
    #pragma unroll
    for (int ks = 0; ks < 4; ++ks)
      w[mt][ks] = *(const bf16x8*)(Wt + (mt * 16 + m) * 128 + ks * 32 + kb * 8);

  for (int tile = gw; tile < 3125; tile += NW){
    long row0 = (long)tile * 16;
    f32x4 acc[8] = {};
    #pragma unroll
    for (int ks = 0; ks < 4; ++ks){
      bf16x8 h = *(const bf16x8*)(Ain + (row0 + m) * 128 + ks * 32 + kb * 8);
      #pragma unroll
      for (int mt = 0; mt < 8; ++mt)
        acc[mt] = __builtin_amdgcn_mfma_f32_16x16x32_bf16(w[mt][ks], h, acc[mt], 0, 0, 0);
    }
    #pragma unroll
    for (int mt = 0; mt < 8; ++mt){
      int c0 = mt * 16 + kb * 4;
      float4 sc = *(const float4*)(SC + c0);
      float4 sh = *(const float4*)(SH + c0);
      float v0 = fmaxf(acc[mt][0] * sc.x + sh.x, 0.f);
      float v1 = fmaxf(acc[mt][1] * sc.y + sh.y, 0.f);
      float v2 = fmaxf(acc[mt][2] * sc.z + sh.z, 0.f);
      float v3 = fmaxf(acc[mt][3] * sc.w + sh.w, 0.f);
      ushort4 o;
      o.x = f2bf(v0); o.y = f2bf(v1); o.z = f2bf(v2); o.w = f2bf(v3);
      *(ushort4*)(Out + (row0 + m) * 128 + c0) = o;
    }
  }
}

// ---------------- mean pool per graph (batch sorted) ----------------
__global__ __launch_bounds__(256) void k_pool(const u16* __restrict__ xb,
                                              const int* __restrict__ batch,
                                              float* __restrict__ pooled){
  int g = blockIdx.x;
  int lo, hi;
  { int a = 0, b = NN; while (a < b){ int mm = (a + b) >> 1; if (batch[mm] < g) a = mm + 1; else b = mm; } lo = a; }
  { int a = lo, b = NN; while (a < b){ int mm = (a + b) >> 1; if (batch[mm] < g + 1) a = mm + 1; else b = mm; } hi = a; }
  int t = threadIdx.x;
  int c = t & 127;
  int half = t >> 7;
  float acc = 0.f;
  for (int i = lo + half; i < hi; i += 2) acc += bf2f(xb[(long)i * 128 + c]);
  __shared__ float s[256];
  s[t] = acc;
  __syncthreads();
  if (t < 128){
    float v = s[t] + s[t + 128];
    int cnt = hi - lo;
    float denom = (cnt > 0) ? (float)cnt : 1.0f;
    pooled[g * 128 + t] = v / denom;
  }
}

// ---------------- head ----------------
__global__ void k_head(const float* __restrict__ pooled, const float* __restrict__ fcw,
                       const float* __restrict__ fcb, float* __restrict__ out){
  int g = threadIdx.x;   // 128 threads, 1 block
  float logit[NC];
  #pragma unroll
  for (int c = 0; c < NC; ++c) logit[c] = fcb[c];
  for (int k = 0; k < 128; ++k){
    float pv = pooled[g * 128 + k];
    #pragma unroll
    for (int c = 0; c < NC; ++c) logit[c] += pv * fcw[k * NC + c];
  }
  float m = logit[0];
  #pragma unroll
  for (int c = 1; c < NC; ++c) m = fmaxf(m, logit[c]);
  float sum = 0.f;
  #pragma unroll
  for (int c = 0; c < NC; ++c) sum += expf(logit[c] - m);
  float ls = logf(sum);
  #pragma unroll
  for (int c = 0; c < NC; ++c) out[g * NC + c] = logit[c] - m - ls;
}

extern "C" void kernel_launch(void* const* d_in, const int* in_sizes, int n_in,
                              void* d_out, int out_size, void* d_ws, size_t ws_size,
                              hipStream_t stream) {
  const float* x     = (const float*)d_in[0];
  const int*   eidx  = (const int*)  d_in[1];
  const int*   batch = (const int*)  d_in[2];
  const float* W1    = (const float*)d_in[3];
  const float* b1    = (const float*)d_in[4];
  const float* W2    = (const float*)d_in[5];
  const float* b2    = (const float*)d_in[6];
  const float* gma   = (const float*)d_in[7];
  const float* bta   = (const float*)d_in[8];
  const float* rmn   = (const float*)d_in[9];
  const float* rvr   = (const float*)d_in[10];
  const float* fcw   = (const float*)d_in[11];
  const float* fcb   = (const float*)d_in[12];
  float* out = (float*)d_out;

  const int* srcI = eidx;          // edge_index[0]
  const int* dstI = eidx + EE;     // edge_index[1]

  // workspace carve
  u16* bufX = (u16*)d_ws;                 // 6.4M elems each (12.8 MB)
  u16* bufA = bufX + 6400000;
  u16* bufB = bufA + 6400000;
  u16* Wt   = bufB + 6400000;             // 6*16384
  float* SC = (float*)(Wt + 98304);       // 768
  float* SH = SC + 768;                   // 768
  float* pooled = SH + 768;               // 16384
  int* adj  = (int*)(pooled + 16384);     // 1.6M
  int* stg  = adj + EE;                   // 1.6M staged packed edges
  int* deg  = stg + EE;
  int* excl = deg + 50048;
  int* rs   = excl + 50048;               // 50001 (+sentinel)
  int* bs   = rs + 50048;                 // 256
  int* bcur = bs + 256;                   // 782*16 padded cursors

  // CSR build
  k_zero_int<<<NB_N, 256, 0, stream>>>(deg, NN);
  k_count   <<<782, 256, 0, stream>>>(dstI, deg);
  k_scan1   <<<NB_N, 256, 0, stream>>>(deg, excl, bs);
  k_scan2   <<<1, 256, 0, stream>>>(bs, NB_N);
  k_scan3   <<<NB_N, 256, 0, stream>>>(rs, bcur, excl, bs);
  k_bin     <<<782, 256, 0, stream>>>(srcI, dstI, bcur, stg);
  k_fill2   <<<782, 256, 0, stream>>>(stg, rs, adj);

  // prep
  k_cvt_x    <<<6250, 256, 0, stream>>>(x, bufX);
  k_prep_w   <<<384, 256, 0, stream>>>(W1, W2, Wt);
  k_prep_scsh<<<3, 256, 0, stream>>>(b1, b2, gma, bta, rmn, rvr, SC, SH);

  // layer schedule (no aliasing hazards):
  // L1: agg X->A ; g0 A->B ; g1 B->A
  // L2: agg A->B ; g0 B->X ; g1 X->B
  // L3: agg B->A ; g0 A->X ; g1 X->A
  u16* aggin [3] = { bufX, bufA, bufB };
  u16* aggout[3] = { bufA, bufB, bufA };
  u16* g0out [3] = { bufB, bufX, bufX };
  u16* g1out [3] = { bufA, bufB, bufA };

  for (int l = 0; l < 3; ++l){
    k_agg <<<6250, 256, 0, stream>>>(aggin[l], aggout[l], adj, rs, deg);
    k_gemm<<<256, 256, 0, stream>>>(aggout[l], Wt + l * 16384,
                                    SC + (l * 2) * 128, SH + (l * 2) * 128, g0out[l]);
    k_gemm<<<256, 256, 0, stream>>>(g0out[l], Wt + (3 + l) * 16384,
                                    SC + (l * 2 + 1) * 128, SH + (l * 2 + 1) * 128, g1out[l]);
  }

  k_pool<<<GG, 256, 0, stream>>>(g1out[2], batch, pooled);
  k_head<<<1, 128, 0, stream>>>(pooled, fcw, fcb, out);
}

// Round 4
// 440.360 us; speedup vs baseline: 2.0285x; 1.3335x over previous
//
#include <hip/hip_runtime.h>

#define NN 50000
#define EE 1600000
#define GG 128
#define NC 10

#define SB_N   49      // superbuckets (dst >> 10)
#define SB_PAD 36864   // padded superbucket region (avg 32653, +23 sigma)
#define BK_N   782     // 64-node buckets (dst >> 6)
#define BK_PAD 2560    // padded bucket region (avg 2046, +11 sigma)
#define CHUNK  4096
#define NBLK1  391     // ceil(EE / CHUNK)
#define SLICES 9       // ceil(SB_PAD / CHUNK)

typedef __attribute__((ext_vector_type(8))) short bf16x8;
typedef __attribute__((ext_vector_type(4))) float f32x4;
typedef unsigned short u16;

__device__ inline u16 f2bf(float x){
  unsigned u = __builtin_bit_cast(unsigned, x);
  u += 0x7fffu + ((u >> 16) & 1u);          // RNE
  return (u16)(u >> 16);
}
__device__ inline float bf2f(u16 u){
  return __builtin_bit_cast(float, ((unsigned)u) << 16);
}

// ---------------- utility ----------------
__global__ void k_zero_int(int* __restrict__ p, int n){
  int i = blockIdx.x * 256 + threadIdx.x;
  if (i < n) p[i] = 0;
}

// ---------------- level-1 scatter: edges -> 49 superbucket regions ----------------
__global__ __launch_bounds__(256) void k_scatL1(const int* __restrict__ srcI, const int* __restrict__ dstI,
                                                int* __restrict__ scur, int* __restrict__ sstg){
  __shared__ int hist[SB_N];
  __shared__ int base[64];
  __shared__ int gadj[SB_N];
  __shared__ unsigned reo[CHUNK];
  int t = threadIdx.x;
  int e0 = blockIdx.x * CHUNK;
  int cnt = EE - e0; if (cnt > CHUNK) cnt = CHUNK;
  if (t < SB_N) hist[t] = 0;
  __syncthreads();
  unsigned p[16]; int rk[16];
  #pragma unroll
  for (int r = 0; r < 16; ++r){
    int i = r * 256 + t;
    if (i < cnt){
      unsigned d = (unsigned)dstI[e0 + i];
      p[r] = (d << 16) | (unsigned)srcI[e0 + i];
      rk[r] = atomicAdd(&hist[d >> 10], 1);
    }
  }
  __syncthreads();
  if (t < 64) base[t] = (t < SB_N) ? hist[t] : 0;
  __syncthreads();
  for (int off = 1; off < 64; off <<= 1){
    int a = (t < 64 && t >= off) ? base[t - off] : 0;
    __syncthreads();
    if (t < 64) base[t] += a;     // inclusive scan
    __syncthreads();
  }
  if (t < SB_N){
    int ex = base[t] - hist[t];   // exclusive
    gadj[t] = atomicAdd(&scur[t], hist[t]) - ex;
  }
  __syncthreads();
  #pragma unroll
  for (int r = 0; r < 16; ++r){
    int i = r * 256 + t;
    if (i < cnt){
      unsigned sb = p[r] >> 26;
      reo[(base[sb] - hist[sb]) + rk[r]] = p[r];
    }
  }
  __syncthreads();
  for (int q = t; q < cnt; q += 256){
    unsigned v = reo[q];
    unsigned sb = v >> 26;
    int off = gadj[sb] + q;       // = gbase + (q - excl)
    if ((unsigned)off < SB_PAD) sstg[sb * SB_PAD + off] = (int)v;
  }
}

// ---------------- level-2 scatter: superbucket -> 16 sub-buckets (64-node) ----------------
__global__ __launch_bounds__(256) void k_scatL2(const int* __restrict__ sstg, const int* __restrict__ scur,
                                                int* __restrict__ bcur, int* __restrict__ bstg){
  __shared__ int hist[16];
  __shared__ int base[16];
  __shared__ int gadj[16];
  __shared__ unsigned reo[CHUNK];
  int t = threadIdx.x;
  int sb = blockIdx.x / SLICES;
  int sl = blockIdx.x % SLICES;
  int ssz = scur[sb]; if (ssz > SB_PAD) ssz = SB_PAD;
  int i0 = sl * CHUNK;
  int cnt = ssz - i0;
  if (cnt <= 0) return;
  if (cnt > CHUNK) cnt = CHUNK;
  if (t < 16) hist[t] = 0;
  __syncthreads();
  unsigned p[16]; int rk[16];
  #pragma unroll
  for (int r = 0; r < 16; ++r){
    int i = r * 256 + t;
    if (i < cnt){
      p[r] = (unsigned)sstg[sb * SB_PAD + i0 + i];
      rk[r] = atomicAdd(&hist[(p[r] >> 22) & 15], 1);
    }
  }
  __syncthreads();
  if (t < 16) base[t] = hist[t];
  __syncthreads();
  for (int off = 1; off < 16; off <<= 1){
    int a = (t < 16 && t >= off) ? base[t - off] : 0;
    __syncthreads();
    if (t < 16) base[t] += a;
    __syncthreads();
  }
  if (t < 16){
    int ex = base[t] - hist[t];
    gadj[t] = atomicAdd(&bcur[sb * 16 + t], hist[t]) - ex;
  }
  __syncthreads();
  #pragma unroll
  for (int r = 0; r < 16; ++r){
    int i = r * 256 + t;
    if (i < cnt){
      unsigned b = (p[r] >> 22) & 15;
      reo[(base[b] - hist[b]) + rk[r]] = p[r];
    }
  }
  __syncthreads();
  for (int q = t; q < cnt; q += 256){
    unsigned v = reo[q];
    unsigned b = (v >> 22) & 15;
    int off = gadj[b] + q;
    if ((unsigned)off < BK_PAD) bstg[(sb * 16 + b) * BK_PAD + off] = (int)v;
  }
}

// ---------------- finalize: per-bucket node grouping -> adj(u16) + ndinfo ----------------
__global__ __launch_bounds__(256) void k_finalize(const int* __restrict__ bstg, const int* __restrict__ bcur,
                                                  u16* __restrict__ adj, int2* __restrict__ ndinfo){
  __shared__ unsigned ebuf[BK_PAD];
  __shared__ int hist[64];
  __shared__ int lrs[64];
  __shared__ int lcur[64];
  int b = blockIdx.x;
  int t = threadIdx.x;
  int bsz = bcur[b]; if (bsz > BK_PAD) bsz = BK_PAD;
  if (t < 64) hist[t] = 0;
  __syncthreads();
  for (int i = t; i < bsz; i += 256){
    unsigned p = (unsigned)bstg[b * BK_PAD + i];
    ebuf[i] = p;
    atomicAdd(&hist[(p >> 16) & 63], 1);
  }
  __syncthreads();
  if (t < 64) lrs[t] = hist[t];
  __syncthreads();
  for (int off = 1; off < 64; off <<= 1){
    int a = (t < 64 && t >= off) ? lrs[t - off] : 0;
    __syncthreads();
    if (t < 64) lrs[t] += a;
    __syncthreads();
  }
  if (t < 64){
    int ex = lrs[t] - hist[t];
    lcur[t] = ex;
    int node = b * 64 + t;
    if (node < NN) ndinfo[node] = make_int2(b * BK_PAD + ex, hist[t]);
  }
  __syncthreads();
  for (int i = t; i < bsz; i += 256){
    unsigned p = ebuf[i];
    int slot = atomicAdd(&lcur[(p >> 16) & 63], 1);
    adj[b * BK_PAD + slot] = (u16)(p & 0xffffu);
  }
}

// ---------------- prep: x->bf16, W->bf16 transposed, BN fold ----------------
__global__ void k_cvt_x(const float* __restrict__ x, u16* __restrict__ xb){
  int i = blockIdx.x * 256 + threadIdx.x;       // grid covers N*128/4 exactly
  float4 v = ((const float4*)x)[i];
  ushort4 o;
  o.x = f2bf(v.x); o.y = f2bf(v.y); o.z = f2bf(v.z); o.w = f2bf(v.w);
  ((ushort4*)xb)[i] = o;
}

__global__ void k_prep_w(const float* __restrict__ W1, const float* __restrict__ W2,
                         u16* __restrict__ Wt){
  int i = blockIdx.x * 256 + threadIdx.x;       // 0..98303
  int a = i >> 14; int r = i & 16383; int n = r >> 7; int k = r & 127;
  const float* Wsrc = (a < 3) ? (W1 + a * 16384) : (W2 + (a - 3) * 16384);
  Wt[a * 16384 + n * 128 + k] = f2bf(Wsrc[k * 128 + n]);
}

__global__ void k_prep_scsh(const float* __restrict__ b1, const float* __restrict__ b2,
                            const float* __restrict__ gma, const float* __restrict__ bta,
                            const float* __restrict__ rmn, const float* __restrict__ rvr,
                            float* __restrict__ SC, float* __restrict__ SH){
  int i = blockIdx.x * 256 + threadIdx.x;
  if (i < 768){
    int l = i >> 8; int r = i & 255; int mode = r >> 7; int c = r & 127;
    if (mode == 0){
      SC[(l * 2) * 128 + c] = 1.0f;
      SH[(l * 2) * 128 + c] = b1[l * 128 + c];
    } else {
      float S = gma[l * 128 + c] * rsqrtf(rvr[l * 128 + c] + 1e-5f);
      SC[(l * 2 + 1) * 128 + c] = S;
      SH[(l * 2 + 1) * 128 + c] = (b2[l * 128 + c] - rmn[l * 128 + c]) * S + bta[l * 128 + c];
    }
  }
}

// ---------------- aggregation (bf16 rows, fp32 accumulate) ----------------
__global__ __launch_bounds__(256) void k_agg(const u16* __restrict__ xb, u16* __restrict__ hb,
                                             const u16* __restrict__ adj,
                                             const int2* __restrict__ ndinfo){
  int t = threadIdx.x;
  int node = blockIdx.x * 8 + (t >> 5);   // grid = 6250 covers NN exactly
  int lane = t & 31;
  const ushort4* xv = (const ushort4*)xb;
  ushort4 sv = xv[(long)node * 32 + lane];
  float a0 = bf2f(sv.x), a1 = bf2f(sv.y), a2 = bf2f(sv.z), a3 = bf2f(sv.w);
  int2 nd = ndinfo[node];
  int r0 = nd.x;
  int d  = nd.y;
  int j = 0;
  for (; j + 4 <= d; j += 4){
    int s0 = adj[r0 + j + 0];
    int s1 = adj[r0 + j + 1];
    int s2 = adj[r0 + j + 2];
    int s3 = adj[r0 + j + 3];
    ushort4 v0 = xv[(long)s0 * 32 + lane];
    ushort4 v1 = xv[(long)s1 * 32 + lane];
    ushort4 v2 = xv[(long)s2 * 32 + lane];
    ushort4 v3 = xv[(long)s3 * 32 + lane];
    a0 += bf2f(v0.x) + bf2f(v1.x) + bf2f(v2.x) + bf2f(v3.x);
    a1 += bf2f(v0.y) + bf2f(v1.y) + bf2f(v2.y) + bf2f(v3.y);
    a2 += bf2f(v0.z) + bf2f(v1.z) + bf2f(v2.z) + bf2f(v3.z);
    a3 += bf2f(v0.w) + bf2f(v1.w) + bf2f(v2.w) + bf2f(v3.w);
  }
  for (; j < d; ++j){
    int s0 = adj[r0 + j];
    ushort4 v0 = xv[(long)s0 * 32 + lane];
    a0 += bf2f(v0.x); a1 += bf2f(v0.y); a2 += bf2f(v0.z); a3 += bf2f(v0.w);
  }
  ushort4 o;
  o.x = f2bf(a0); o.y = f2bf(a1); o.z = f2bf(a2); o.w = f2bf(a3);
  ((ushort4*)hb)[(long)node * 32 + lane] = o;
}

// ---------------- MFMA GEMM: Out = relu(A@W * SC + SH), all [*][128] ----------------
__global__ __launch_bounds__(256, 2) void k_gemm(const u16* __restrict__ Ain,
                                                 const u16* __restrict__ Wt,
                                                 const float* __restrict__ SC,
                                                 const float* __restrict__ SH,
                                                 u16* __restrict__ Out){
  int gw = (blockIdx.x * 256 + threadIdx.x) >> 6;
  int l  = threadIdx.x & 63;
  int m  = l & 15;
  int kb = l >> 4;
  const int NW = (gridDim.x * 256) >> 6;

  bf16x8 w[8][4];
  #pragma unroll
  for (int mt = 0; mt < 8; ++mt)
    #pragma unroll
    for (int ks = 0; ks < 4; ++ks)
      w[mt][ks] = *(const bf16x8*)(Wt + (mt * 16 + m) * 128 + ks * 32 + kb * 8);

  for (int tile = gw; tile < 3125; tile += NW){
    long row0 = (long)tile * 16;
    f32x4 acc[8] = {};
    #pragma unroll
    for (int ks = 0; ks < 4; ++ks){
      bf16x8 h = *(const bf16x8*)(Ain + (row0 + m) * 128 + ks * 32 + kb * 8);
      #pragma unroll
      for (int mt = 0; mt < 8; ++mt)
        acc[mt] = __builtin_amdgcn_mfma_f32_16x16x32_bf16(w[mt][ks], h, acc[mt], 0, 0, 0);
    }
    #pragma unroll
    for (int mt = 0; mt < 8; ++mt){
      int c0 = mt * 16 + kb * 4;
      float4 sc = *(const float4*)(SC + c0);
      float4 sh = *(const float4*)(SH + c0);
      float v0 = fmaxf(acc[mt][0] * sc.x + sh.x, 0.f);
      float v1 = fmaxf(acc[mt][1] * sc.y + sh.y, 0.f);
      float v2 = fmaxf(acc[mt][2] * sc.z + sh.z, 0.f);
      float v3 = fmaxf(acc[mt][3] * sc.w + sh.w, 0.f);
      ushort4 o;
      o.x = f2bf(v0); o.y = f2bf(v1); o.z = f2bf(v2); o.w = f2bf(v3);
      *(ushort4*)(Out + (row0 + m) * 128 + c0) = o;
    }
  }
}

// ---------------- mean pool per graph (batch sorted) ----------------
__global__ __launch_bounds__(256) void k_pool(const u16* __restrict__ xb,
                                              const int* __restrict__ batch,
                                              float* __restrict__ pooled){
  int g = blockIdx.x;
  int lo, hi;
  { int a = 0, b = NN; while (a < b){ int mm = (a + b) >> 1; if (batch[mm] < g) a = mm + 1; else b = mm; } lo = a; }
  { int a = lo, b = NN; while (a < b){ int mm = (a + b) >> 1; if (batch[mm] < g + 1) a = mm + 1; else b = mm; } hi = a; }
  int t = threadIdx.x;
  int c = t & 127;
  int half = t >> 7;
  float acc = 0.f;
  for (int i = lo + half; i < hi; i += 2) acc += bf2f(xb[(long)i * 128 + c]);
  __shared__ float s[256];
  s[t] = acc;
  __syncthreads();
  if (t < 128){
    float v = s[t] + s[t + 128];
    int cnt = hi - lo;
    float denom = (cnt > 0) ? (float)cnt : 1.0f;
    pooled[g * 128 + t] = v / denom;
  }
}

// ---------------- head ----------------
__global__ void k_head(const float* __restrict__ pooled, const float* __restrict__ fcw,
                       const float* __restrict__ fcb, float* __restrict__ out){
  int g = threadIdx.x;   // 128 threads, 1 block
  float logit[NC];
  #pragma unroll
  for (int c = 0; c < NC; ++c) logit[c] = fcb[c];
  for (int k = 0; k < 128; ++k){
    float pv = pooled[g * 128 + k];
    #pragma unroll
    for (int c = 0; c < NC; ++c) logit[c] += pv * fcw[k * NC + c];
  }
  float m = logit[0];
  #pragma unroll
  for (int c = 1; c < NC; ++c) m = fmaxf(m, logit[c]);
  float sum = 0.f;
  #pragma unroll
  for (int c = 0; c < NC; ++c) sum += expf(logit[c] - m);
  float ls = logf(sum);
  #pragma unroll
  for (int c = 0; c < NC; ++c) out[g * NC + c] = logit[c] - m - ls;
}

extern "C" void kernel_launch(void* const* d_in, const int* in_sizes, int n_in,
                              void* d_out, int out_size, void* d_ws, size_t ws_size,
                              hipStream_t stream) {
  const float* x     = (const float*)d_in[0];
  const int*   eidx  = (const int*)  d_in[1];
  const int*   batch = (const int*)  d_in[2];
  const float* W1    = (const float*)d_in[3];
  const float* b1    = (const float*)d_in[4];
  const float* W2    = (const float*)d_in[5];
  const float* b2    = (const float*)d_in[6];
  const float* gma   = (const float*)d_in[7];
  const float* bta   = (const float*)d_in[8];
  const float* rmn   = (const float*)d_in[9];
  const float* rvr   = (const float*)d_in[10];
  const float* fcw   = (const float*)d_in[11];
  const float* fcb   = (const float*)d_in[12];
  float* out = (float*)d_out;

  const int* srcI = eidx;          // edge_index[0]
  const int* dstI = eidx + EE;     // edge_index[1]

  // workspace carve
  u16* bufX = (u16*)d_ws;                   // 6.4M u16 each (12.8 MB)
  u16* bufA = bufX + 6400000;
  u16* bufB = bufA + 6400000;
  u16* Wt   = bufB + 6400000;               // 6*16384
  float* SC = (float*)(Wt + 98304);         // 768
  float* SH = SC + 768;                     // 768
  float* pooled = SH + 768;                 // 16384
  u16* adj  = (u16*)(pooled + 16384);       // 782*2560 u16 (padded, bucket-local)
  int2* ndinfo = (int2*)(adj + (BK_N * BK_PAD)); // 50048 (start, deg)
  int* ctr  = (int*)(ndinfo + 50048);       // scur[64] + bcur[784]
  int* scur = ctr;
  int* bcur = ctr + 64;
  // staging aliases (dead before bufA/bufB are first written)
  int* sstg = (int*)bufA;                   // 49*36864 ints = 7.2 MB <= 12.8
  int* bstg = (int*)bufB;                   // 784*2560 ints = 8.0 MB <= 12.8

  // CSR build (LDS-staged two-level scatter)
  k_zero_int<<<4, 256, 0, stream>>>(ctr, 64 + 784);
  k_scatL1  <<<NBLK1, 256, 0, stream>>>(srcI, dstI, scur, sstg);
  k_scatL2  <<<SB_N * SLICES, 256, 0, stream>>>(sstg, scur, bcur, bstg);
  k_finalize<<<BK_N, 256, 0, stream>>>(bstg, bcur, adj, ndinfo);

  // prep
  k_cvt_x    <<<6250, 256, 0, stream>>>(x, bufX);
  k_prep_w   <<<384, 256, 0, stream>>>(W1, W2, Wt);
  k_prep_scsh<<<3, 256, 0, stream>>>(b1, b2, gma, bta, rmn, rvr, SC, SH);

  // layer schedule (no aliasing hazards):
  // L1: agg X->A ; g0 A->B ; g1 B->A      (sstg alias bufA dead; bstg alias bufB dead)
  // L2: agg A->B ; g0 B->X ; g1 X->B
  // L3: agg B->A ; g0 A->X ; g1 X->A
  u16* aggin [3] = { bufX, bufA, bufB };
  u16* aggout[3] = { bufA, bufB, bufA };
  u16* g0out [3] = { bufB, bufX, bufX };
  u16* g1out [3] = { bufA, bufB, bufA };

  for (int l = 0; l < 3; ++l){
    k_agg <<<6250, 256, 0, stream>>>(aggin[l], aggout[l], adj, ndinfo);
    k_gemm<<<256, 256, 0, stream>>>(aggout[l], Wt + l * 16384,
                                    SC + (l * 2) * 128, SH + (l * 2) * 128, g0out[l]);
    k_gemm<<<256, 256, 0, stream>>>(g0out[l], Wt + (3 + l) * 16384,
                                    SC + (l * 2 + 1) * 128, SH + (l * 2 + 1) * 128, g1out[l]);
  }

  k_pool<<<GG, 256, 0, stream>>>(g1out[2], batch, pooled);
  k_head<<<1, 128, 0, stream>>>(pooled, fcw, fcb, out);
}

// Round 5
// 416.530 us; speedup vs baseline: 2.1446x; 1.0572x over previous
//
#include <hip/hip_runtime.h>

#define NN 50000
#define EE 1600000
#define GG 128
#define NC 10

#define SB_N   49      // superbuckets (dst >> 10)
#define SB_PAD 36864   // padded superbucket region (avg 32653)
#define BK_N   782     // 64-node buckets (dst >> 6)
#define BK_PAD 2560    // padded bucket region (avg 2046)
#define CHUNK  4096
#define NBLK1  391     // ceil(EE / CHUNK)
#define SLICES 9       // ceil(SB_PAD / CHUNK)

typedef __attribute__((ext_vector_type(8))) short bf16x8;
typedef __attribute__((ext_vector_type(4))) float f32x4;
typedef unsigned short u16;

__device__ inline u16 f2bf(float x){
  unsigned u = __builtin_bit_cast(unsigned, x);
  u += 0x7fffu + ((u >> 16) & 1u);          // RNE
  return (u16)(u >> 16);
}
__device__ inline float bf2f(u16 u){
  return __builtin_bit_cast(float, ((unsigned)u) << 16);
}

// ---------------- utility ----------------
__global__ void k_zero_int(int* __restrict__ p, int n){
  int i = blockIdx.x * 256 + threadIdx.x;
  if (i < n) p[i] = 0;
}

// ---------------- level-1 scatter: edges -> 49 superbucket regions ----------------
__global__ __launch_bounds__(256) void k_scatL1(const int* __restrict__ srcI, const int* __restrict__ dstI,
                                                int* __restrict__ scur, int* __restrict__ sstg){
  __shared__ int hist[SB_N];
  __shared__ int base[64];
  __shared__ int gadj[SB_N];
  __shared__ unsigned reo[CHUNK];
  int t = threadIdx.x;
  int e0 = blockIdx.x * CHUNK;
  int cnt = EE - e0; if (cnt > CHUNK) cnt = CHUNK;
  if (t < SB_N) hist[t] = 0;
  __syncthreads();
  unsigned p[16]; int rk[16];
  #pragma unroll
  for (int r = 0; r < 16; ++r){
    int i = r * 256 + t;
    if (i < cnt){
      unsigned d = (unsigned)dstI[e0 + i];
      p[r] = (d << 16) | (unsigned)srcI[e0 + i];
      rk[r] = atomicAdd(&hist[d >> 10], 1);
    }
  }
  __syncthreads();
  if (t < 64) base[t] = (t < SB_N) ? hist[t] : 0;
  __syncthreads();
  for (int off = 1; off < 64; off <<= 1){
    int a = (t < 64 && t >= off) ? base[t - off] : 0;
    __syncthreads();
    if (t < 64) base[t] += a;     // inclusive scan
    __syncthreads();
  }
  if (t < SB_N){
    int ex = base[t] - hist[t];   // exclusive
    gadj[t] = atomicAdd(&scur[t], hist[t]) - ex;
  }
  __syncthreads();
  #pragma unroll
  for (int r = 0; r < 16; ++r){
    int i = r * 256 + t;
    if (i < cnt){
      unsigned sb = p[r] >> 26;
      reo[(base[sb] - hist[sb]) + rk[r]] = p[r];
    }
  }
  __syncthreads();
  for (int q = t; q < cnt; q += 256){
    unsigned v = reo[q];
    unsigned sb = v >> 26;
    int off = gadj[sb] + q;       // = gbase + (q - excl)
    if ((unsigned)off < SB_PAD) sstg[sb * SB_PAD + off] = (int)v;
  }
}

// ---------------- level-2 scatter: superbucket -> 16 sub-buckets (64-node) ----------------
__global__ __launch_bounds__(256) void k_scatL2(const int* __restrict__ sstg, const int* __restrict__ scur,
                                                int* __restrict__ bcur, int* __restrict__ bstg){
  __shared__ int hist[16];
  __shared__ int base[16];
  __shared__ int gadj[16];
  __shared__ unsigned reo[CHUNK];
  int t = threadIdx.x;
  int sb = blockIdx.x / SLICES;
  int sl = blockIdx.x % SLICES;
  int ssz = scur[sb]; if (ssz > SB_PAD) ssz = SB_PAD;
  int i0 = sl * CHUNK;
  int cnt = ssz - i0;
  if (cnt <= 0) return;
  if (cnt > CHUNK) cnt = CHUNK;
  if (t < 16) hist[t] = 0;
  __syncthreads();
  unsigned p[16]; int rk[16];
  #pragma unroll
  for (int r = 0; r < 16; ++r){
    int i = r * 256 + t;
    if (i < cnt){
      p[r] = (unsigned)sstg[sb * SB_PAD + i0 + i];
      rk[r] = atomicAdd(&hist[(p[r] >> 22) & 15], 1);
    }
  }
  __syncthreads();
  if (t < 16) base[t] = hist[t];
  __syncthreads();
  for (int off = 1; off < 16; off <<= 1){
    int a = (t < 16 && t >= off) ? base[t - off] : 0;
    __syncthreads();
    if (t < 16) base[t] += a;
    __syncthreads();
  }
  if (t < 16){
    int ex = base[t] - hist[t];
    gadj[t] = atomicAdd(&bcur[sb * 16 + t], hist[t]) - ex;
  }
  __syncthreads();
  #pragma unroll
  for (int r = 0; r < 16; ++r){
    int i = r * 256 + t;
    if (i < cnt){
      unsigned b = (p[r] >> 22) & 15;
      reo[(base[b] - hist[b]) + rk[r]] = p[r];
    }
  }
  __syncthreads();
  for (int q = t; q < cnt; q += 256){
    unsigned v = reo[q];
    unsigned b = (v >> 22) & 15;
    int off = gadj[b] + q;
    if ((unsigned)off < BK_PAD) bstg[(sb * 16 + b) * BK_PAD + off] = (int)v;
  }
}

// ---------------- finalize: per-bucket node grouping -> adj(u16) + ndinfo ----------------
__global__ __launch_bounds__(256) void k_finalize(const int* __restrict__ bstg, const int* __restrict__ bcur,
                                                  u16* __restrict__ adj, int2* __restrict__ ndinfo){
  __shared__ unsigned ebuf[BK_PAD];
  __shared__ int hist[64];
  __shared__ int lrs[64];
  __shared__ int lcur[64];
  int b = blockIdx.x;
  int t = threadIdx.x;
  int bsz = bcur[b]; if (bsz > BK_PAD) bsz = BK_PAD;
  if (t < 64) hist[t] = 0;
  __syncthreads();
  for (int i = t; i < bsz; i += 256){
    unsigned p = (unsigned)bstg[b * BK_PAD + i];
    ebuf[i] = p;
    atomicAdd(&hist[(p >> 16) & 63], 1);
  }
  __syncthreads();
  if (t < 64) lrs[t] = hist[t];
  __syncthreads();
  for (int off = 1; off < 64; off <<= 1){
    int a = (t < 64 && t >= off) ? lrs[t - off] : 0;
    __syncthreads();
    if (t < 64) lrs[t] += a;
    __syncthreads();
  }
  if (t < 64){
    int ex = lrs[t] - hist[t];
    lcur[t] = ex;
    int node = b * 64 + t;
    if (node < NN) ndinfo[node] = make_int2(b * BK_PAD + ex, hist[t]);
  }
  __syncthreads();
  for (int i = t; i < bsz; i += 256){
    unsigned p = ebuf[i];
    int slot = atomicAdd(&lcur[(p >> 16) & 63], 1);
    adj[b * BK_PAD + slot] = (u16)(p & 0xffffu);
  }
}

// ---------------- prep: x->bf16, W->bf16 transposed, BN fold ----------------
__global__ void k_cvt_x(const float* __restrict__ x, u16* __restrict__ xb){
  int i = blockIdx.x * 256 + threadIdx.x;       // grid covers N*128/4 exactly
  float4 v = ((const float4*)x)[i];
  ushort4 o;
  o.x = f2bf(v.x); o.y = f2bf(v.y); o.z = f2bf(v.z); o.w = f2bf(v.w);
  ((ushort4*)xb)[i] = o;
}

__global__ void k_prep_w(const float* __restrict__ W1, const float* __restrict__ W2,
                         u16* __restrict__ Wt){
  int i = blockIdx.x * 256 + threadIdx.x;       // 0..98303
  int a = i >> 14; int r = i & 16383; int n = r >> 7; int k = r & 127;
  const float* Wsrc = (a < 3) ? (W1 + a * 16384) : (W2 + (a - 3) * 16384);
  Wt[a * 16384 + n * 128 + k] = f2bf(Wsrc[k * 128 + n]);
}

__global__ void k_prep_scsh(const float* __restrict__ b1, const float* __restrict__ b2,
                            const float* __restrict__ gma, const float* __restrict__ bta,
                            const float* __restrict__ rmn, const float* __restrict__ rvr,
                            float* __restrict__ SC, float* __restrict__ SH){
  int i = blockIdx.x * 256 + threadIdx.x;
  if (i < 768){
    int l = i >> 8; int r = i & 255; int mode = r >> 7; int c = r & 127;
    if (mode == 0){
      SC[(l * 2) * 128 + c] = 1.0f;
      SH[(l * 2) * 128 + c] = b1[l * 128 + c];
    } else {
      float S = gma[l * 128 + c] * rsqrtf(rvr[l * 128 + c] + 1e-5f);
      SC[(l * 2 + 1) * 128 + c] = S;
      SH[(l * 2 + 1) * 128 + c] = (b2[l * 128 + c] - rmn[l * 128 + c]) * S + bta[l * 128 + c];
    }
  }
}

// ---------------- aggregation: 16 lanes/node, bf16x8 (16B) gathers ----------------
__global__ __launch_bounds__(256) void k_agg(const u16* __restrict__ xb, u16* __restrict__ hb,
                                             const u16* __restrict__ adj,
                                             const int2* __restrict__ ndinfo){
  int t = threadIdx.x;
  int node = blockIdx.x * 16 + (t >> 4);   // grid = 3125 covers NN exactly
  int lane = t & 15;
  const bf16x8* xv = (const bf16x8*)xb;    // 16 bf16x8 per 128-wide row
  bf16x8 sv = xv[(long)node * 16 + lane];
  float a[8];
  #pragma unroll
  for (int j = 0; j < 8; ++j) a[j] = bf2f((u16)sv[j]);
  int2 nd = ndinfo[node];
  int r0 = nd.x;
  int d  = nd.y;
  int j = 0;
  for (; j + 4 <= d; j += 4){
    int s0 = adj[r0 + j + 0];
    int s1 = adj[r0 + j + 1];
    int s2 = adj[r0 + j + 2];
    int s3 = adj[r0 + j + 3];
    bf16x8 v0 = xv[(long)s0 * 16 + lane];
    bf16x8 v1 = xv[(long)s1 * 16 + lane];
    bf16x8 v2 = xv[(long)s2 * 16 + lane];
    bf16x8 v3 = xv[(long)s3 * 16 + lane];
    #pragma unroll
    for (int q = 0; q < 8; ++q)
      a[q] += bf2f((u16)v0[q]) + bf2f((u16)v1[q]) + bf2f((u16)v2[q]) + bf2f((u16)v3[q]);
  }
  for (; j < d; ++j){
    int s0 = adj[r0 + j];
    bf16x8 v0 = xv[(long)s0 * 16 + lane];
    #pragma unroll
    for (int q = 0; q < 8; ++q) a[q] += bf2f((u16)v0[q]);
  }
  bf16x8 o;
  #pragma unroll
  for (int j2 = 0; j2 < 8; ++j2) o[j2] = (short)f2bf(a[j2]);
  ((bf16x8*)hb)[(long)node * 16 + lane] = o;
}

// ---------------- MFMA GEMM: Out = relu(A@W * SC + SH), all [*][128] ----------------
__global__ __launch_bounds__(256, 2) void k_gemm(const u16* __restrict__ Ain,
                                                 const u16* __restrict__ Wt,
                                                 const float* __restrict__ SC,
                                                 const float* __restrict__ SH,
                                                 u16* __restrict__ Out){
  int gw = (blockIdx.x * 256 + threadIdx.x) >> 6;
  int l  = threadIdx.x & 63;
  int m  = l & 15;
  int kb = l >> 4;
  const int NW = (gridDim.x * 256) >> 6;

  bf16x8 w[8][4];
  #pragma unroll
  for (int mt = 0; mt < 8; ++mt)
    #pragma unroll
    for (int ks = 0; ks < 4; ++ks)
      w[mt][ks] = *(const bf16x8*)(Wt + (mt * 16 + m) * 128 + ks * 32 + kb * 8);

  for (int tile = gw; tile < 3125; tile += NW){
    long row0 = (long)tile * 16;
    f32x4 acc[8] = {};
    #pragma unroll
    for (int ks = 0; ks < 4; ++ks){
      bf16x8 h = *(const bf16x8*)(Ain + (row0 + m) * 128 + ks * 32 + kb * 8);
      #pragma unroll
      for (int mt = 0; mt < 8; ++mt)
        acc[mt] = __builtin_amdgcn_mfma_f32_16x16x32_bf16(w[mt][ks], h, acc[mt], 0, 0, 0);
    }
    #pragma unroll
    for (int mt = 0; mt < 8; ++mt){
      int c0 = mt * 16 + kb * 4;
      float4 sc = *(const float4*)(SC + c0);
      float4 sh = *(const float4*)(SH + c0);
      float v0 = fmaxf(acc[mt][0] * sc.x + sh.x, 0.f);
      float v1 = fmaxf(acc[mt][1] * sc.y + sh.y, 0.f);
      float v2 = fmaxf(acc[mt][2] * sc.z + sh.z, 0.f);
      float v3 = fmaxf(acc[mt][3] * sc.w + sh.w, 0.f);
      ushort4 o;
      o.x = f2bf(v0); o.y = f2bf(v1); o.z = f2bf(v2); o.w = f2bf(v3);
      *(ushort4*)(Out + (row0 + m) * 128 + c0) = o;
    }
  }
}

// ---------------- pool: 782 blocks, per-bucket partials -> atomic fp32 accumulate ----------------
__global__ __launch_bounds__(256) void k_pool(const u16* __restrict__ xb,
                                              const int* __restrict__ batch,
                                              float* __restrict__ pooled){
  __shared__ float4 red[8][32];
  int b = blockIdx.x;
  int n0 = b << 6;
  int t = threadIdx.x;
  int lane = t & 31;
  int rg = t >> 5;
  int g0 = batch[n0];
  int lastn = n0 + 63; if (lastn >= NN) lastn = NN - 1;
  int nk = batch[lastn] - g0;          // graph offsets present in this block
  const ushort4* xv = (const ushort4*)xb;
  float4 a0 = {0,0,0,0}, a1 = {0,0,0,0}, a2 = {0,0,0,0};
  int rbase = n0 + rg * 8;
  #pragma unroll
  for (int i = 0; i < 8; ++i){
    int r = rbase + i;
    if (r >= NN) break;
    int k = batch[r] - g0;
    ushort4 v = xv[(long)r * 32 + lane];
    float fx = bf2f(v.x), fy = bf2f(v.y), fz = bf2f(v.z), fw = bf2f(v.w);
    if (k == 0){ a0.x += fx; a0.y += fy; a0.z += fz; a0.w += fw; }
    else if (k == 1){ a1.x += fx; a1.y += fy; a1.z += fz; a1.w += fw; }
    else if (k == 2){ a2.x += fx; a2.y += fy; a2.z += fz; a2.w += fw; }
    else {
      float* pg = pooled + (g0 + k) * 128 + lane * 4;
      atomicAdd(pg + 0, fx); atomicAdd(pg + 1, fy);
      atomicAdd(pg + 2, fz); atomicAdd(pg + 3, fw);
    }
  }
  int kmax = (nk < 2) ? nk : 2;
  for (int k = 0; k <= kmax; ++k){
    red[rg][lane] = (k == 0) ? a0 : ((k == 1) ? a1 : a2);
    __syncthreads();
    if (t < 32){
      float4 s = red[0][t];
      #pragma unroll
      for (int r = 1; r < 8; ++r){
        float4 q = red[r][t];
        s.x += q.x; s.y += q.y; s.z += q.z; s.w += q.w;
      }
      float* pg = pooled + (g0 + k) * 128 + t * 4;
      atomicAdd(pg + 0, s.x); atomicAdd(pg + 1, s.y);
      atomicAdd(pg + 2, s.z); atomicAdd(pg + 3, s.w);
    }
    __syncthreads();
  }
}

// ---------------- head: counts via binary search + logits + log_softmax ----------------
__global__ void k_head(const float* __restrict__ pooled, const float* __restrict__ fcw,
                       const float* __restrict__ fcb, const int* __restrict__ batch,
                       float* __restrict__ out){
  int g = threadIdx.x;   // 128 threads, 1 block
  int lo, hi;
  { int a = 0, b = NN; while (a < b){ int mm = (a + b) >> 1; if (batch[mm] < g) a = mm + 1; else b = mm; } lo = a; }
  { int a = lo, b = NN; while (a < b){ int mm = (a + b) >> 1; if (batch[mm] < g + 1) a = mm + 1; else b = mm; } hi = a; }
  float inv = 1.0f / fmaxf((float)(hi - lo), 1.0f);
  float logit[NC];
  #pragma unroll
  for (int c = 0; c < NC; ++c) logit[c] = fcb[c];
  for (int k = 0; k < 128; ++k){
    float pv = pooled[g * 128 + k] * inv;
    #pragma unroll
    for (int c = 0; c < NC; ++c) logit[c] += pv * fcw[k * NC + c];
  }
  float m = logit[0];
  #pragma unroll
  for (int c = 1; c < NC; ++c) m = fmaxf(m, logit[c]);
  float sum = 0.f;
  #pragma unroll
  for (int c = 0; c < NC; ++c) sum += expf(logit[c] - m);
  float ls = logf(sum);
  #pragma unroll
  for (int c = 0; c < NC; ++c) out[g * NC + c] = logit[c] - m - ls;
}

extern "C" void kernel_launch(void* const* d_in, const int* in_sizes, int n_in,
                              void* d_out, int out_size, void* d_ws, size_t ws_size,
                              hipStream_t stream) {
  const float* x     = (const float*)d_in[0];
  const int*   eidx  = (const int*)  d_in[1];
  const int*   batch = (const int*)  d_in[2];
  const float* W1    = (const float*)d_in[3];
  const float* b1    = (const float*)d_in[4];
  const float* W2    = (const float*)d_in[5];
  const float* b2    = (const float*)d_in[6];
  const float* gma   = (const float*)d_in[7];
  const float* bta   = (const float*)d_in[8];
  const float* rmn   = (const float*)d_in[9];
  const float* rvr   = (const float*)d_in[10];
  const float* fcw   = (const float*)d_in[11];
  const float* fcb   = (const float*)d_in[12];
  float* out = (float*)d_out;

  const int* srcI = eidx;          // edge_index[0]
  const int* dstI = eidx + EE;     // edge_index[1]

  // workspace carve
  u16* bufX = (u16*)d_ws;                   // 6.4M u16 each (12.8 MB)
  u16* bufA = bufX + 6400000;
  u16* bufB = bufA + 6400000;
  u16* Wt   = bufB + 6400000;               // 6*16384
  float* SC = (float*)(Wt + 98304);         // 768
  float* SH = SC + 768;                     // 768
  float* pooled = SH + 768;                 // 16384 fp32 (atomic accumulator)
  int* ctr  = (int*)(pooled + 16384);       // scur[64] + bcur[784]  (adjacent to pooled)
  int* scur = ctr;
  int* bcur = ctr + 64;
  u16* adj  = (u16*)(ctr + 848);            // 782*2560 u16 (padded, bucket-local)
  int2* ndinfo = (int2*)(adj + (BK_N * BK_PAD)); // 50048 (start, deg)
  // staging aliases (dead before bufA/bufB are first written)
  int* sstg = (int*)bufA;                   // 49*36864 ints = 7.2 MB <= 12.8
  int* bstg = (int*)bufB;                   // 784*2560 ints = 8.0 MB <= 12.8

  // zero pooled + counters in one pass (17232 ints)
  k_zero_int<<<68, 256, 0, stream>>>((int*)pooled, 16384 + 848);

  // CSR build (LDS-staged two-level scatter)
  k_scatL1  <<<NBLK1, 256, 0, stream>>>(srcI, dstI, scur, sstg);
  k_scatL2  <<<SB_N * SLICES, 256, 0, stream>>>(sstg, scur, bcur, bstg);
  k_finalize<<<BK_N, 256, 0, stream>>>(bstg, bcur, adj, ndinfo);

  // prep
  k_cvt_x    <<<6250, 256, 0, stream>>>(x, bufX);
  k_prep_w   <<<384, 256, 0, stream>>>(W1, W2, Wt);
  k_prep_scsh<<<3, 256, 0, stream>>>(b1, b2, gma, bta, rmn, rvr, SC, SH);

  // layer schedule (no aliasing hazards):
  // L1: agg X->A ; g0 A->B ; g1 B->A      (sstg alias bufA dead; bstg alias bufB dead)
  // L2: agg A->B ; g0 B->X ; g1 X->B
  // L3: agg B->A ; g0 A->X ; g1 X->A
  u16* aggin [3] = { bufX, bufA, bufB };
  u16* aggout[3] = { bufA, bufB, bufA };
  u16* g0out [3] = { bufB, bufX, bufX };
  u16* g1out [3] = { bufA, bufB, bufA };

  for (int l = 0; l < 3; ++l){
    k_agg <<<3125, 256, 0, stream>>>(aggin[l], aggout[l], adj, ndinfo);
    k_gemm<<<256, 256, 0, stream>>>(aggout[l], Wt + l * 16384,
                                    SC + (l * 2) * 128, SH + (l * 2) * 128, g0out[l]);
    k_gemm<<<256, 256, 0, stream>>>(g0out[l], Wt + (3 + l) * 16384,
                                    SC + (l * 2 + 1) * 128, SH + (l * 2 + 1) * 128, g1out[l]);
  }

  k_pool<<<BK_N, 256, 0, stream>>>(g1out[2], batch, pooled);
  k_head<<<1, 128, 0, stream>>>(pooled, fcw, fcb, batch, out);
}